// Round 1
// baseline (1591.133 us; speedup 1.0000x reference)
//
#include <hip/hip_runtime.h>
#include <math.h>

#define S_LEN 2048
#define HID   2048
#define NH    32
#define NKV   8
#define HD    64
#define KVD   (NKV*HD)   // 512
#define GQA   (NH/NKV)   // 4

// ---------------------------------------------------------------------------
// Tiled fp32 GEMM: C[M,N] = A[M,K] @ B[K,N], row-major. BM=BN=64, BK=16,
// 256 threads, 4x4 micro-tile per thread. M,N mult of 64; K mult of 16.
// ---------------------------------------------------------------------------
__global__ __launch_bounds__(256)
void gemm_f32(const float* __restrict__ A, const float* __restrict__ B,
              float* __restrict__ C, int M, int N, int K) {
    __shared__ float As[64][17];   // +1 pad
    __shared__ float Bs[16][64];
    const int t  = threadIdx.x;
    const int tx = t & 15;         // 0..15  -> 4 cols each
    const int ty = t >> 4;         // 0..15  -> 4 rows each
    const int row0 = blockIdx.y * 64;
    const int col0 = blockIdx.x * 64;

    float acc[4][4];
#pragma unroll
    for (int i = 0; i < 4; ++i)
#pragma unroll
        for (int j = 0; j < 4; ++j) acc[i][j] = 0.f;

    for (int k0 = 0; k0 < K; k0 += 16) {
        // A tile 64x16: thread t loads A[row0 + t/4][k0 + (t%4)*4 ..+3]
        {
            const int r = t >> 2, c = (t & 3) << 2;
            float4 v = *(const float4*)(A + (size_t)(row0 + r) * K + k0 + c);
            As[r][c + 0] = v.x; As[r][c + 1] = v.y;
            As[r][c + 2] = v.z; As[r][c + 3] = v.w;
        }
        // B tile 16x64: thread t loads B[k0 + t/16][col0 + (t%16)*4 ..+3]
        {
            const int r = t >> 4, c = (t & 15) << 2;
            float4 v = *(const float4*)(B + (size_t)(k0 + r) * N + col0 + c);
            Bs[r][c + 0] = v.x; Bs[r][c + 1] = v.y;
            Bs[r][c + 2] = v.z; Bs[r][c + 3] = v.w;
        }
        __syncthreads();
#pragma unroll
        for (int kk = 0; kk < 16; ++kk) {
            float a[4], b[4];
#pragma unroll
            for (int i = 0; i < 4; ++i) a[i] = As[ty * 4 + i][kk];
#pragma unroll
            for (int j = 0; j < 4; ++j) b[j] = Bs[kk][tx * 4 + j];
#pragma unroll
            for (int i = 0; i < 4; ++i)
#pragma unroll
                for (int j = 0; j < 4; ++j) acc[i][j] += a[i] * b[j];
        }
        __syncthreads();
    }
#pragma unroll
    for (int i = 0; i < 4; ++i) {
        float* dst = C + (size_t)(row0 + ty * 4 + i) * N + col0 + tx * 4;
#pragma unroll
        for (int j = 0; j < 4; ++j) dst[j] = acc[i][j];
    }
}

// ---------------------------------------------------------------------------
// RoPE in-place on X: [S, nheads*HD]. One thread per (s, h, d<32) pair.
// x'[d]    = x[d]*cos - x[d+32]*sin
// x'[d+32] = x[d+32]*cos + x[d]*sin,  angle = pos * theta^(-2d/64)
// ---------------------------------------------------------------------------
__global__ void rope_kernel(float* __restrict__ X, const int* __restrict__ pos_ids,
                            int nheads) {
    const int idx = blockIdx.x * blockDim.x + threadIdx.x;
    const int total = S_LEN * nheads * (HD / 2);
    if (idx >= total) return;
    const int d = idx % (HD / 2);
    const int h = (idx / (HD / 2)) % nheads;
    const int s = idx / ((HD / 2) * nheads);

    const float pos = (float)pos_ids[s];
    const float expo = (float)(2 * d) / (float)HD;
    const float inv_freq = powf(500000.0f, -expo);
    const float ang = pos * inv_freq;
    const float c = cosf(ang), sn = sinf(ang);

    float* p = X + (size_t)s * (nheads * HD) + h * HD;
    const float x0 = p[d], x1 = p[d + 32];
    p[d]      = x0 * c - x1 * sn;
    p[d + 32] = x1 * c + x0 * sn;
}

// ---------------------------------------------------------------------------
// Causal flash attention, fp32.  grid = (S/64, NH), 256 threads.
// Q pre-scaled by 1/8 at load. 64x64 Q tile per block; iterate KV tiles of 64
// with online softmax (row stats in LDS, computed by wave 0).
// ---------------------------------------------------------------------------
__global__ __launch_bounds__(256)
void attn_kernel(const float* __restrict__ Q, const float* __restrict__ K,
                 const float* __restrict__ V, float* __restrict__ Ctx) {
    __shared__ float Qs[64][HD + 1];
    __shared__ float Ks[64][HD + 1];
    __shared__ float Vs[64][HD + 1];
    __shared__ float Ss[64][65];
    __shared__ float m_s[64], l_s[64], alpha_s[64];

    const int t = threadIdx.x;
    const int qtile = blockIdx.x;
    const int h = blockIdx.y;
    const int kh = h / GQA;
    const int q0 = qtile * 64;

    // load + scale Q tile (1024 float4s / 256 threads = 4 each)
    const float scale = 0.125f;   // 1/sqrt(64)
    for (int f = t; f < 64 * 16; f += 256) {
        const int r = f >> 4, c4 = (f & 15) << 2;
        float4 v = *(const float4*)(Q + (size_t)(q0 + r) * HID + h * HD + c4);
        Qs[r][c4 + 0] = v.x * scale; Qs[r][c4 + 1] = v.y * scale;
        Qs[r][c4 + 2] = v.z * scale; Qs[r][c4 + 3] = v.w * scale;
    }
    if (t < 64) { m_s[t] = -1e30f; l_s[t] = 0.f; }

    // 4x4 register blocking for scores and O-update
    const int sr = (t >> 4) << 2;   // rows   sr..sr+3
    const int sc = (t & 15) << 2;   // cols   sc..sc+3
    float o[4][4];
#pragma unroll
    for (int i = 0; i < 4; ++i)
#pragma unroll
        for (int j = 0; j < 4; ++j) o[i][j] = 0.f;

    const int ntiles = qtile + 1;
    for (int jt = 0; jt < ntiles; ++jt) {
        const int jbase = jt * 64;
        __syncthreads();   // prev iter's reads of Ks/Vs/Ss done
        for (int f = t; f < 64 * 16; f += 256) {
            const int r = f >> 4, c4 = (f & 15) << 2;
            float4 kv = *(const float4*)(K + (size_t)(jbase + r) * KVD + kh * HD + c4);
            Ks[r][c4 + 0] = kv.x; Ks[r][c4 + 1] = kv.y;
            Ks[r][c4 + 2] = kv.z; Ks[r][c4 + 3] = kv.w;
            float4 vv = *(const float4*)(V + (size_t)(jbase + r) * KVD + kh * HD + c4);
            Vs[r][c4 + 0] = vv.x; Vs[r][c4 + 1] = vv.y;
            Vs[r][c4 + 2] = vv.z; Vs[r][c4 + 3] = vv.w;
        }
        __syncthreads();

        // scores: acc[i][j] = Qs[sr+i][:] . Ks[sc+j][:]
        float acc[4][4];
#pragma unroll
        for (int i = 0; i < 4; ++i)
#pragma unroll
            for (int j = 0; j < 4; ++j) acc[i][j] = 0.f;
        for (int d = 0; d < HD; ++d) {
            float a[4], b[4];
#pragma unroll
            for (int i = 0; i < 4; ++i) a[i] = Qs[sr + i][d];
#pragma unroll
            for (int j = 0; j < 4; ++j) b[j] = Ks[sc + j][d];
#pragma unroll
            for (int i = 0; i < 4; ++i)
#pragma unroll
                for (int j = 0; j < 4; ++j) acc[i][j] += a[i] * b[j];
        }
        const bool diag = (jt == qtile);
#pragma unroll
        for (int i = 0; i < 4; ++i)
#pragma unroll
            for (int j = 0; j < 4; ++j) {
                float v = acc[i][j];
                if (diag && (jbase + sc + j) > (q0 + sr + i)) v = -1e30f;
                Ss[sr + i][sc + j] = v;
            }
        __syncthreads();

        // row stats + exp in place (one wave)
        if (t < 64) {
            float tmax = -1e30f;
            for (int c = 0; c < 64; ++c) tmax = fmaxf(tmax, Ss[t][c]);
            const float mold = m_s[t];
            const float mnew = fmaxf(mold, tmax);
            const float alpha = __expf(mold - mnew);
            float psum = 0.f;
            for (int c = 0; c < 64; ++c) {
                const float p = __expf(Ss[t][c] - mnew);
                Ss[t][c] = p;
                psum += p;
            }
            m_s[t] = mnew;
            l_s[t] = alpha * l_s[t] + psum;
            alpha_s[t] = alpha;
        }
        __syncthreads();

        // O update: o[i][j] = alpha*o[i][j] + P[sr+i][:] @ Vs[:][sc+j]
#pragma unroll
        for (int i = 0; i < 4; ++i) {
            const float a = alpha_s[sr + i];
#pragma unroll
            for (int j = 0; j < 4; ++j) o[i][j] *= a;
        }
        for (int k = 0; k < 64; ++k) {
            float p[4], v[4];
#pragma unroll
            for (int i = 0; i < 4; ++i) p[i] = Ss[sr + i][k];
#pragma unroll
            for (int j = 0; j < 4; ++j) v[j] = Vs[k][sc + j];
#pragma unroll
            for (int i = 0; i < 4; ++i)
#pragma unroll
                for (int j = 0; j < 4; ++j) o[i][j] += p[i] * v[j];
        }
    }

    // epilogue: normalize and write Ctx[s][h*64 + c]
#pragma unroll
    for (int i = 0; i < 4; ++i) {
        const float inv_l = 1.f / l_s[sr + i];
        float* dst = Ctx + (size_t)(q0 + sr + i) * HID + h * HD + sc;
#pragma unroll
        for (int j = 0; j < 4; ++j) dst[j] = o[i][j] * inv_l;
    }
}

// ---------------------------------------------------------------------------
extern "C" void kernel_launch(void* const* d_in, const int* in_sizes, int n_in,
                              void* d_out, int out_size, void* d_ws, size_t ws_size,
                              hipStream_t stream) {
    const float* X   = (const float*)d_in[0];
    const int*   pos = (const int*)d_in[1];
    const float* Wq  = (const float*)d_in[2];
    const float* Wk  = (const float*)d_in[3];
    const float* Wv  = (const float*)d_in[4];
    const float* Wo  = (const float*)d_in[5];
    float* out = (float*)d_out;

    float* Q   = (float*)d_ws;                    // 2048*2048
    float* Kb  = Q  + (size_t)S_LEN * HID;        // 2048*512
    float* Vb  = Kb + (size_t)S_LEN * KVD;        // 2048*512
    float* Ctx = Vb + (size_t)S_LEN * KVD;        // 2048*2048

    dim3 blk(256);
    gemm_f32<<<dim3(HID / 64, S_LEN / 64), blk, 0, stream>>>(X, Wq, Q,  S_LEN, HID, HID);
    gemm_f32<<<dim3(KVD / 64, S_LEN / 64), blk, 0, stream>>>(X, Wk, Kb, S_LEN, KVD, HID);
    gemm_f32<<<dim3(KVD / 64, S_LEN / 64), blk, 0, stream>>>(X, Wv, Vb, S_LEN, KVD, HID);

    rope_kernel<<<(S_LEN * NH  * (HD / 2) + 255) / 256, blk, 0, stream>>>(Q,  pos, NH);
    rope_kernel<<<(S_LEN * NKV * (HD / 2) + 255) / 256, blk, 0, stream>>>(Kb, pos, NKV);

    attn_kernel<<<dim3(S_LEN / 64, NH), blk, 0, stream>>>(Q, Kb, Vb, Ctx);

    gemm_f32<<<dim3(HID / 64, S_LEN / 64), blk, 0, stream>>>(Ctx, Wo, out, S_LEN, HID, HID);
}

// Round 2
// 375.896 us; speedup vs baseline: 4.2329x; 4.2329x over previous
//
#include <hip/hip_runtime.h>
#include <hip/hip_bf16.h>
#include <math.h>

#define S_LEN 2048
#define HID   2048
#define NH    32
#define NKV   8
#define HD    64
#define QKVD  3072   // Q[0:2048] | K[2048:2560] | V[2560:3072]
#define GQA   4

typedef unsigned short u16;
typedef __attribute__((ext_vector_type(8))) short short8;   // 8 bf16 = 4 VGPRs (MFMA A/B frag)
typedef __attribute__((ext_vector_type(4))) float f32x4;    // MFMA C/D frag

__device__ __forceinline__ u16 f2bf(float x) {
    union { __hip_bfloat16 b; u16 u; } c; c.b = __float2bfloat16(x); return c.u;
}
__device__ __forceinline__ float bf2f(u16 u) {
    union { unsigned int i; float f; } c; c.i = ((unsigned int)u) << 16; return c.f;
}
// async global->LDS, 16B per lane. HW semantics: wave-uniform LDS base + lane*16.
// Passing base+lane*16 per-lane is correct under readfirstlane (lane 0 = base).
__device__ __forceinline__ void async_copy16(void* lds, const void* g) {
    __builtin_amdgcn_global_load_lds((const __attribute__((address_space(1))) unsigned int*)g,
                                     (__attribute__((address_space(3))) unsigned int*)lds,
                                     16, 0, 0);
}

// ---------------------------------------------------------------------------
// fp32 -> bf16 cast, 8 elems/thread
// ---------------------------------------------------------------------------
__global__ __launch_bounds__(256)
void cast_bf16(const float* __restrict__ in, u16* __restrict__ out, int n8) {
    int i = blockIdx.x * blockDim.x + threadIdx.x;
    if (i >= n8) return;
    const float4* p = (const float4*)(in + (size_t)i * 8);
    float4 a = p[0], b = p[1];
    short8 o;
    o[0] = f2bf(a.x); o[1] = f2bf(a.y); o[2] = f2bf(a.z); o[3] = f2bf(a.w);
    o[4] = f2bf(b.x); o[5] = f2bf(b.y); o[6] = f2bf(b.z); o[7] = f2bf(b.w);
    *(short8*)(out + (size_t)i * 8) = o;
}

// ---------------------------------------------------------------------------
// transpose + cast: W fp32 [Kin][Nin] -> WT bf16 [Nin][Kin]
// ---------------------------------------------------------------------------
__global__ __launch_bounds__(256)
void transpose_cast(const float* __restrict__ W, u16* __restrict__ WT, int Kin, int Nin) {
    __shared__ float tile[32][33];
    const int tx = threadIdx.x & 31, ty = threadIdx.x >> 5;
    const int x = blockIdx.x * 32 + tx;     // col in W
#pragma unroll
    for (int j = ty; j < 32; j += 8)
        tile[j][tx] = W[(size_t)(blockIdx.y * 32 + j) * Nin + x];
    __syncthreads();
    const int xo = blockIdx.y * 32 + tx;    // col in WT (= row in W)
#pragma unroll
    for (int j = ty; j < 32; j += 8)
        WT[(size_t)(blockIdx.x * 32 + j) * Kin + xo] = f2bf(tile[tx][j]);
}

// ---------------------------------------------------------------------------
// RoPE in-place on bf16 QKV buffer; outscale folds in attention 1/sqrt(D) for Q
// ---------------------------------------------------------------------------
__global__ __launch_bounds__(256)
void rope_bf16(u16* __restrict__ Qkv, const int* __restrict__ pos,
               int nheads, int colOff, float outscale) {
    int idx = blockIdx.x * blockDim.x + threadIdx.x;
    int d = idx & 31;
    int h = (idx >> 5) % nheads;
    int s = idx / (32 * nheads);
    if (s >= S_LEN) return;
    float p = (float)pos[s];
    float inv_freq = powf(500000.0f, -(float)(2 * d) / 64.0f);
    float ang = p * inv_freq;
    float c = cosf(ang), sn = sinf(ang);
    u16* b = Qkv + (size_t)s * QKVD + colOff + h * HD;
    float x0 = bf2f(b[d]), x1 = bf2f(b[d + 32]);
    b[d]      = f2bf((x0 * c - x1 * sn) * outscale);
    b[d + 32] = f2bf((x1 * c + x0 * sn) * outscale);
}

// ---------------------------------------------------------------------------
// m97-style bf16 GEMM: C[M,N] = A[M,K] @ Bt[N,K]^T. 128x128 tile, BK=32,
// 256 thr / 4 waves, each wave 64x64 (4x4 of 16x16x32 MFMA). global_load_lds.
// ---------------------------------------------------------------------------
template<bool BF16_OUT>
__global__ __launch_bounds__(256)
void gemm_bt(const u16* __restrict__ A, const u16* __restrict__ Bt,
             void* __restrict__ Cv, int M, int N, int K) {
    __shared__ u16 As[128 * 32];
    __shared__ u16 Bs[128 * 32];
    const int t = threadIdx.x;
    const int lane = t & 63;
    const int w = t >> 6;
    const int lm = lane & 15, quad = lane >> 4;
    const int row0 = blockIdx.y * 128, col0 = blockIdx.x * 128;
    const int wr = (w >> 1) * 64, wc = (w & 1) * 64;

    f32x4 acc[4][4];
#pragma unroll
    for (int i = 0; i < 4; ++i)
#pragma unroll
        for (int j = 0; j < 4; ++j) acc[i][j] = (f32x4){0.f, 0.f, 0.f, 0.f};

    const size_t strideB = (size_t)K * 2;   // bytes per row
    for (int k0 = 0; k0 < K; k0 += 32) {
        __syncthreads();
        const char* Ab = (const char*)(A + (size_t)row0 * K + k0);
        const char* Bb = (const char*)(Bt + (size_t)col0 * K + k0);
#pragma unroll
        for (int i = 0; i < 2; ++i) {
            const int f = i * 4096 + t * 16;           // byte offset in 8KB tile
            const int r = f >> 6, cb = f & 63;         // 64B rows
            async_copy16((char*)As + f, Ab + (size_t)r * strideB + cb);
            async_copy16((char*)Bs + f, Bb + (size_t)r * strideB + cb);
        }
        __syncthreads();
        short8 af[4], bfv[4];
#pragma unroll
        for (int i = 0; i < 4; ++i)
            af[i] = *(const short8*)((const char*)As + (wr + 16 * i + lm) * 64 + quad * 16);
#pragma unroll
        for (int j = 0; j < 4; ++j)
            bfv[j] = *(const short8*)((const char*)Bs + (wc + 16 * j + lm) * 64 + quad * 16);
#pragma unroll
        for (int i = 0; i < 4; ++i)
#pragma unroll
            for (int j = 0; j < 4; ++j)
                acc[i][j] = __builtin_amdgcn_mfma_f32_16x16x32_bf16(af[i], bfv[j], acc[i][j], 0, 0, 0);
    }
    // C/D layout: col = lane&15, row = quad*4 + reg  [m89-verified]
    const int cr = quad * 4, cc = lm;
#pragma unroll
    for (int i = 0; i < 4; ++i) {
        const int gr = row0 + wr + 16 * i + cr;
#pragma unroll
        for (int j = 0; j < 4; ++j) {
            const int gc = col0 + wc + 16 * j + cc;
#pragma unroll
            for (int rr = 0; rr < 4; ++rr) {
                if (BF16_OUT) ((u16*)Cv)[(size_t)(gr + rr) * N + gc] = f2bf(acc[i][j][rr]);
                else          ((float*)Cv)[(size_t)(gr + rr) * N + gc] = acc[i][j][rr];
            }
        }
    }
}

// ---------------------------------------------------------------------------
// MFMA flash attention. grid=(S/64, NH), 256 thr / 4 waves.
// Wave w owns q-rows [16w,16w+16) -> online-softmax state is wave-private.
// Q/K LDS tiles split into two 32-elem k-slabs (64B rows: async-stageable AND
// conflict-free frag reads). Vt/Ps use padded stride 72 (144B rows, 2-way).
// ---------------------------------------------------------------------------
__global__ __launch_bounds__(256)
void attn_mfma(const u16* __restrict__ Qkv, u16* __restrict__ Ctx) {
    __shared__ u16 Qs[2 * 64 * 32];
    __shared__ u16 Ks[2 * 64 * 32];
    __shared__ u16 Vt[64 * 72];   // [d][kv]
    __shared__ u16 Ps[64 * 72];   // [q][kv]

    const int t = threadIdx.x;
    const int lane = t & 63;
    const int w = t >> 6;
    const int lm = lane & 15, quad = lane >> 4;
    const int qt = blockIdx.x, h = blockIdx.y;
    const int kh = h >> 2;             // GQA group
    const int q0 = qt * 64;

    const u16* Qbase = Qkv + h * HD;
    const u16* Kbase = Qkv + 2048 + kh * HD;
    const u16* Vbase = Qkv + 2560 + kh * HD;

    // stage Q (two 32-elem half-slabs; i selects the half)
#pragma unroll
    for (int i = 0; i < 2; ++i) {
        const int f = i * 4096 + t * 16;
        const int r = w * 16 + (lane >> 2);                 // tile row
        const int cb = (lane & 3) * 16;                     // byte within 64B half-row
        async_copy16((char*)Qs + f,
                     (const char*)(Qbase + (size_t)(q0 + r) * QKVD) + i * 64 + cb);
    }
    __syncthreads();   // drains vmcnt: Q resident

    short8 qf0 = *(const short8*)((const char*)Qs +        (w * 16 + lm) * 64 + quad * 16);
    short8 qf1 = *(const short8*)((const char*)Qs + 4096 + (w * 16 + lm) * 64 + quad * 16);

    float m_i[4], l_i[4];
    f32x4 acc_o[4];
#pragma unroll
    for (int r = 0; r < 4; ++r) { m_i[r] = -1e30f; l_i[r] = 0.f; acc_o[r] = (f32x4){0.f,0.f,0.f,0.f}; }

    for (int jt = 0; jt <= qt; ++jt) {
        const int j0 = jt * 64;
        __syncthreads();   // prior iter's Ks/Vt reads complete
        // stage K (async, half-slab layout)
#pragma unroll
        for (int i = 0; i < 2; ++i) {
            const int f = i * 4096 + t * 16;
            const int r = w * 16 + (lane >> 2);
            const int cb = (lane & 3) * 16;
            async_copy16((char*)Ks + f,
                         (const char*)(Kbase + (size_t)(j0 + r) * QKVD) + i * 64 + cb);
        }
        // stage V transposed: lane = kv row s, wave w covers d in [16w,16w+16)
        {
            const int s = lane, d0 = w * 16;
            const u16* vp = Vbase + (size_t)(j0 + s) * QKVD + d0;
            short8 v0 = *(const short8*)(vp);
            short8 v1 = *(const short8*)(vp + 8);
#pragma unroll
            for (int j = 0; j < 8; ++j) Vt[(d0 + j) * 72 + s] = (u16)v0[j];
#pragma unroll
            for (int j = 0; j < 8; ++j) Vt[(d0 + 8 + j) * 72 + s] = (u16)v1[j];
        }
        __syncthreads();   // staging visible (vmcnt+lgkmcnt drained by barrier)

        // S = Q K^T : wave's 16 rows x 64 cols, 8 MFMAs
        f32x4 sacc[4];
#pragma unroll
        for (int ct = 0; ct < 4; ++ct) sacc[ct] = (f32x4){0.f, 0.f, 0.f, 0.f};
#pragma unroll
        for (int ct = 0; ct < 4; ++ct) {
            short8 kf0 = *(const short8*)((const char*)Ks +        (ct * 16 + lm) * 64 + quad * 16);
            short8 kf1 = *(const short8*)((const char*)Ks + 4096 + (ct * 16 + lm) * 64 + quad * 16);
            sacc[ct] = __builtin_amdgcn_mfma_f32_16x16x32_bf16(qf0, kf0, sacc[ct], 0, 0, 0);
            sacc[ct] = __builtin_amdgcn_mfma_f32_16x16x32_bf16(qf1, kf1, sacc[ct], 0, 0, 0);
        }
        // causal mask on diagonal tile
        if (jt == qt) {
#pragma unroll
            for (int ct = 0; ct < 4; ++ct) {
                const int col = j0 + ct * 16 + lm;
#pragma unroll
                for (int r = 0; r < 4; ++r)
                    if (col > q0 + w * 16 + quad * 4 + r) sacc[ct][r] = -1e30f;
            }
        }
        // online softmax: rows quad*4+r, replicated across the 16-lane quad group
        float mnew[4], alpha[4], psum[4];
#pragma unroll
        for (int r = 0; r < 4; ++r) {
            float vm = fmaxf(fmaxf(sacc[0][r], sacc[1][r]), fmaxf(sacc[2][r], sacc[3][r]));
            vm = fmaxf(vm, __shfl_xor(vm, 1));
            vm = fmaxf(vm, __shfl_xor(vm, 2));
            vm = fmaxf(vm, __shfl_xor(vm, 4));
            vm = fmaxf(vm, __shfl_xor(vm, 8));
            mnew[r] = fmaxf(m_i[r], vm);
            alpha[r] = __expf(m_i[r] - mnew[r]);
            m_i[r] = mnew[r];
            psum[r] = 0.f;
        }
#pragma unroll
        for (int ct = 0; ct < 4; ++ct)
#pragma unroll
            for (int r = 0; r < 4; ++r) {
                float p = __expf(sacc[ct][r] - mnew[r]);
                sacc[ct][r] = p;
                psum[r] += p;
            }
#pragma unroll
        for (int r = 0; r < 4; ++r) {
            float ps = psum[r];
            ps += __shfl_xor(ps, 1);
            ps += __shfl_xor(ps, 2);
            ps += __shfl_xor(ps, 4);
            ps += __shfl_xor(ps, 8);
            l_i[r] = alpha[r] * l_i[r] + ps;
        }
        // P -> LDS (bf16, wave-private rows: HW in-order LDS, no barrier needed)
#pragma unroll
        for (int ct = 0; ct < 4; ++ct)
#pragma unroll
            for (int r = 0; r < 4; ++r)
                Ps[(w * 16 + quad * 4 + r) * 72 + ct * 16 + lm] = f2bf(sacc[ct][r]);
        // rescale O
#pragma unroll
        for (int dt = 0; dt < 4; ++dt)
#pragma unroll
            for (int r = 0; r < 4; ++r) acc_o[dt][r] *= alpha[r];
        // O += P V : 8 MFMAs
        short8 pf0 = *(const short8*)((const char*)Ps + (w * 16 + lm) * 144 + quad * 16);
        short8 pf1 = *(const short8*)((const char*)Ps + (w * 16 + lm) * 144 + 64 + quad * 16);
#pragma unroll
        for (int dt = 0; dt < 4; ++dt) {
            short8 vf0 = *(const short8*)((const char*)Vt + (dt * 16 + lm) * 144 + quad * 16);
            short8 vf1 = *(const short8*)((const char*)Vt + (dt * 16 + lm) * 144 + 64 + quad * 16);
            acc_o[dt] = __builtin_amdgcn_mfma_f32_16x16x32_bf16(pf0, vf0, acc_o[dt], 0, 0, 0);
            acc_o[dt] = __builtin_amdgcn_mfma_f32_16x16x32_bf16(pf1, vf1, acc_o[dt], 0, 0, 0);
        }
    }
    // epilogue: normalize, write bf16 Ctx[row][h*64 + d]
#pragma unroll
    for (int r = 0; r < 4; ++r) {
        const float inv = 1.f / l_i[r];
        const int row = q0 + w * 16 + quad * 4 + r;
#pragma unroll
        for (int dt = 0; dt < 4; ++dt)
            Ctx[(size_t)row * HID + h * HD + dt * 16 + lm] = f2bf(acc_o[dt][r] * inv);
    }
}

// ---------------------------------------------------------------------------
extern "C" void kernel_launch(void* const* d_in, const int* in_sizes, int n_in,
                              void* d_out, int out_size, void* d_ws, size_t ws_size,
                              hipStream_t stream) {
    const float* X  = (const float*)d_in[0];
    const int*   pos = (const int*)d_in[1];
    const float* Wq = (const float*)d_in[2];
    const float* Wk = (const float*)d_in[3];
    const float* Wv = (const float*)d_in[4];
    const float* Wo = (const float*)d_in[5];
    float* out = (float*)d_out;

    // ws layout (bf16 elems): Xb 4M | WqkvT 6M | WoT 4M | QKV 6M  = 40 MB
    u16* Xb    = (u16*)d_ws;
    u16* WqkvT = Xb + (size_t)4194304;
    u16* WoT   = WqkvT + (size_t)6291456;
    u16* QKV   = WoT + (size_t)4194304;
    u16* Ctxb  = Xb;   // Xb dead after QKV GEMM; reuse for context

    cast_bf16<<<2048, 256, 0, stream>>>(X, Xb, 524288);
    transpose_cast<<<dim3(64, 64), 256, 0, stream>>>(Wq, WqkvT, 2048, 2048);
    transpose_cast<<<dim3(16, 64), 256, 0, stream>>>(Wk, WqkvT + (size_t)2048 * 2048, 2048, 512);
    transpose_cast<<<dim3(16, 64), 256, 0, stream>>>(Wv, WqkvT + (size_t)2560 * 2048, 2048, 512);
    transpose_cast<<<dim3(64, 64), 256, 0, stream>>>(Wo, WoT, 2048, 2048);

    gemm_bt<true><<<dim3(24, 16), 256, 0, stream>>>(Xb, WqkvT, QKV, 2048, QKVD, 2048);

    rope_bf16<<<8192, 256, 0, stream>>>(QKV, pos, NH, 0, 0.125f);      // Q (+1/sqrt(D))
    rope_bf16<<<2048, 256, 0, stream>>>(QKV, pos, NKV, 2048, 1.0f);    // K

    attn_mfma<<<dim3(S_LEN / 64, NH), 256, 0, stream>>>(QKV, Ctxb);

    gemm_bt<false><<<dim3(16, 16), 256, 0, stream>>>(Ctxb, WoT, out, 2048, 2048, 2048);
}

// Round 3
// 353.351 us; speedup vs baseline: 4.5030x; 1.0638x over previous
//
#include <hip/hip_runtime.h>
#include <hip/hip_bf16.h>
#include <math.h>

#define S_LEN 2048
#define HID   2048
#define NH    32
#define NKV   8
#define HD    64
#define QKD   2560   // QK buffer row stride: Q[0:2048] | K[2048:2560]
#define GQA   4
#define LOG2E 1.44269504f

typedef unsigned short u16;
typedef __attribute__((ext_vector_type(8))) short short8;   // 8 bf16 (MFMA A/B frag)
typedef __attribute__((ext_vector_type(4))) float f32x4;    // MFMA C/D frag

__device__ __forceinline__ u16 f2bf(float x) {
    union { __hip_bfloat16 b; u16 u; } c; c.b = __float2bfloat16(x); return c.u;
}
__device__ __forceinline__ float bf2f(u16 u) {
    union { unsigned int i; float f; } c; c.i = ((unsigned int)u) << 16; return c.f;
}
__device__ __forceinline__ void async_copy16(void* lds, const void* g) {
    __builtin_amdgcn_global_load_lds((const __attribute__((address_space(1))) unsigned int*)g,
                                     (__attribute__((address_space(3))) unsigned int*)lds,
                                     16, 0, 0);
}

// ---------------------------------------------------------------------------
__global__ __launch_bounds__(256)
void cast_bf16(const float* __restrict__ in, u16* __restrict__ out, int n8) {
    int i = blockIdx.x * blockDim.x + threadIdx.x;
    if (i >= n8) return;
    const float4* p = (const float4*)(in + (size_t)i * 8);
    float4 a = p[0], b = p[1];
    short8 o;
    o[0] = f2bf(a.x); o[1] = f2bf(a.y); o[2] = f2bf(a.z); o[3] = f2bf(a.w);
    o[4] = f2bf(b.x); o[5] = f2bf(b.y); o[6] = f2bf(b.z); o[7] = f2bf(b.w);
    *(short8*)(out + (size_t)i * 8) = o;
}

// ---------------------------------------------------------------------------
__global__ __launch_bounds__(256)
void transpose_cast(const float* __restrict__ W, u16* __restrict__ WT, int Kin, int Nin) {
    __shared__ float tile[32][33];
    const int tx = threadIdx.x & 31, ty = threadIdx.x >> 5;
    const int x = blockIdx.x * 32 + tx;
#pragma unroll
    for (int j = ty; j < 32; j += 8)
        tile[j][tx] = W[(size_t)(blockIdx.y * 32 + j) * Nin + x];
    __syncthreads();
    const int xo = blockIdx.y * 32 + tx;
#pragma unroll
    for (int j = ty; j < 32; j += 8)
        WT[(size_t)(blockIdx.x * 32 + j) * Kin + xo] = f2bf(tile[tx][j]);
}

// ---------------------------------------------------------------------------
// Fused RoPE over Q (heads 0..31) and K (heads 32..39): col = hh*64 works for
// both since K head 0 sits at col 2048. Q gets 1/sqrt(64)*log2(e) folded in
// (scores then feed exp2 directly).
// ---------------------------------------------------------------------------
__global__ __launch_bounds__(256)
void rope_qk(u16* __restrict__ QK, const int* __restrict__ pos) {
    int idx = blockIdx.x * blockDim.x + threadIdx.x;
    int d = idx & 31;
    int hh = (idx >> 5) % 40;
    int s = idx / (32 * 40);
    if (s >= S_LEN) return;
    float p = (float)pos[s];
    float inv_freq = powf(500000.0f, -(float)(2 * d) / 64.0f);
    float ang = p * inv_freq;
    float c = cosf(ang), sn = sinf(ang);
    float sc = (hh < 32) ? 0.125f * LOG2E : 1.0f;
    u16* b = QK + (size_t)s * QKD + hh * HD;
    float x0 = bf2f(b[d]), x1 = bf2f(b[d + 32]);
    b[d]      = f2bf((x0 * c - x1 * sn) * sc);
    b[d + 32] = f2bf((x1 * c + x0 * sn) * sc);
}

// ---------------------------------------------------------------------------
// m97-style bf16 GEMM: C = A[M,K] @ Bt[N,K]^T. 128x128 tile, BK=32.
// MODE 0: fp32 C, stride N.  MODE 1: QKV epilogue — cols <2560 -> bf16 QK
// (stride 2560); cols >=2560 -> V written TRANSPOSED to Vt[d][s] (vectorized:
// the 4 acc regs are s-contiguous).
// ---------------------------------------------------------------------------
template<int MODE>
__global__ __launch_bounds__(256)
void gemm_bt(const u16* __restrict__ A, const u16* __restrict__ Bt,
             void* __restrict__ Cv, u16* __restrict__ Vt, int M, int N, int K) {
    __shared__ u16 As[128 * 32];
    __shared__ u16 Bs[128 * 32];
    const int t = threadIdx.x;
    const int lane = t & 63;
    const int w = t >> 6;
    const int lm = lane & 15, quad = lane >> 4;
    const int row0 = blockIdx.y * 128, col0 = blockIdx.x * 128;
    const int wr = (w >> 1) * 64, wc = (w & 1) * 64;

    f32x4 acc[4][4];
#pragma unroll
    for (int i = 0; i < 4; ++i)
#pragma unroll
        for (int j = 0; j < 4; ++j) acc[i][j] = (f32x4){0.f, 0.f, 0.f, 0.f};

    const size_t strideB = (size_t)K * 2;
    for (int k0 = 0; k0 < K; k0 += 32) {
        __syncthreads();
        const char* Ab = (const char*)(A + (size_t)row0 * K + k0);
        const char* Bb = (const char*)(Bt + (size_t)col0 * K + k0);
#pragma unroll
        for (int i = 0; i < 2; ++i) {
            const int f = i * 4096 + t * 16;
            const int r = f >> 6, cb = f & 63;
            async_copy16((char*)As + f, Ab + (size_t)r * strideB + cb);
            async_copy16((char*)Bs + f, Bb + (size_t)r * strideB + cb);
        }
        __syncthreads();
        short8 af[4], bfv[4];
#pragma unroll
        for (int i = 0; i < 4; ++i)
            af[i] = *(const short8*)((const char*)As + (wr + 16 * i + lm) * 64 + quad * 16);
#pragma unroll
        for (int j = 0; j < 4; ++j)
            bfv[j] = *(const short8*)((const char*)Bs + (wc + 16 * j + lm) * 64 + quad * 16);
#pragma unroll
        for (int i = 0; i < 4; ++i)
#pragma unroll
            for (int j = 0; j < 4; ++j)
                acc[i][j] = __builtin_amdgcn_mfma_f32_16x16x32_bf16(af[i], bfv[j], acc[i][j], 0, 0, 0);
    }
    const int cr = quad * 4, cc = lm;
#pragma unroll
    for (int i = 0; i < 4; ++i) {
        const int gr = row0 + wr + 16 * i + cr;
#pragma unroll
        for (int j = 0; j < 4; ++j) {
            const int gc = col0 + wc + 16 * j + cc;
            if (MODE == 0) {
#pragma unroll
                for (int rr = 0; rr < 4; ++rr)
                    ((float*)Cv)[(size_t)(gr + rr) * N + gc] = acc[i][j][rr];
            } else if (gc < 2560) {
#pragma unroll
                for (int rr = 0; rr < 4; ++rr)
                    ((u16*)Cv)[(size_t)(gr + rr) * QKD + gc] = f2bf(acc[i][j][rr]);
            } else {
                const int d = gc - 2560;
                ushort4 vv;
                vv.x = f2bf(acc[i][j][0]); vv.y = f2bf(acc[i][j][1]);
                vv.z = f2bf(acc[i][j][2]); vv.w = f2bf(acc[i][j][3]);
                *(ushort4*)(Vt + (size_t)d * S_LEN + gr) = vv;
            }
        }
    }
}

// ---------------------------------------------------------------------------
// MFMA flash attention. grid=(32 qtiles, 32 heads), 256 thr / 4 waves.
// qt reversed (LPT: longest blocks first). Wave w owns q-rows [16w,16w+16).
// K and pre-transposed V staged async (two 32-elem slabs, 64B rows).
// Q LDS reused for P (wave-private rows); Ps stride 136B -> conflict-free.
// Scores are in log2 domain (Q pre-scaled by 0.125*log2e) -> exp2.
// ---------------------------------------------------------------------------
__global__ __launch_bounds__(256)
void attn_mfma(const u16* __restrict__ QK, const u16* __restrict__ Vtg,
               u16* __restrict__ Ctx) {
    __shared__ u16 QPs[4352];   // 8704B: Q staging (8192B) then P (64 rows x 136B)
    __shared__ u16 Ks[4096];    // 8KB
    __shared__ u16 Vts[4096];   // 8KB

    const int t = threadIdx.x;
    const int lane = t & 63;
    const int w = t >> 6;
    const int lm = lane & 15, quad = lane >> 4;
    const int qt = (gridDim.x - 1) - blockIdx.x;   // longest first
    const int h = blockIdx.y;
    const int kh = h >> 2;
    const int q0 = qt * 64;

    const char* Qb = (const char*)(QK + h * HD);
    const char* Kb = (const char*)(QK + 2048 + kh * HD);
    const char* Vb = (const char*)(Vtg + (size_t)(kh * 64) * S_LEN);

    // stage Q: two 32-elem slabs, 64B rows
    {
        const int r = t >> 2, cb = (t & 3) * 16;
#pragma unroll
        for (int i = 0; i < 2; ++i)
            async_copy16((char*)QPs + i * 4096 + t * 16,
                         Qb + (size_t)(q0 + r) * (QKD * 2) + i * 64 + cb);
    }
    __syncthreads();
    short8 qf0 = *(const short8*)((const char*)QPs +        (w * 16 + lm) * 64 + quad * 16);
    short8 qf1 = *(const short8*)((const char*)QPs + 4096 + (w * 16 + lm) * 64 + quad * 16);

    float m_i[4], l_i[4];
    f32x4 acc_o[4];
#pragma unroll
    for (int r = 0; r < 4; ++r) { m_i[r] = -1e30f; l_i[r] = 0.f; acc_o[r] = (f32x4){0.f,0.f,0.f,0.f}; }

    for (int jt = 0; jt <= qt; ++jt) {
        const int j0 = jt * 64;
        __syncthreads();   // prior iter's Ks/Vts reads complete
        {
            const int r = t >> 2, cb = (t & 3) * 16;
#pragma unroll
            for (int i = 0; i < 2; ++i) {
                async_copy16((char*)Ks + i * 4096 + t * 16,
                             Kb + (size_t)(j0 + r) * (QKD * 2) + i * 64 + cb);
                async_copy16((char*)Vts + i * 4096 + t * 16,
                             Vb + (size_t)r * (S_LEN * 2) + j0 * 2 + i * 64 + cb);
            }
        }
        __syncthreads();   // staging visible

        // S = Q K^T (log2 domain): 16 rows x 64 cols per wave, 8 MFMAs
        f32x4 sacc[4];
#pragma unroll
        for (int ct = 0; ct < 4; ++ct) sacc[ct] = (f32x4){0.f, 0.f, 0.f, 0.f};
#pragma unroll
        for (int ct = 0; ct < 4; ++ct) {
            short8 kf0 = *(const short8*)((const char*)Ks +        (ct * 16 + lm) * 64 + quad * 16);
            short8 kf1 = *(const short8*)((const char*)Ks + 4096 + (ct * 16 + lm) * 64 + quad * 16);
            sacc[ct] = __builtin_amdgcn_mfma_f32_16x16x32_bf16(qf0, kf0, sacc[ct], 0, 0, 0);
            sacc[ct] = __builtin_amdgcn_mfma_f32_16x16x32_bf16(qf1, kf1, sacc[ct], 0, 0, 0);
        }
        if (jt == qt) {
#pragma unroll
            for (int ct = 0; ct < 4; ++ct) {
                const int col = j0 + ct * 16 + lm;
#pragma unroll
                for (int r = 0; r < 4; ++r)
                    if (col > q0 + w * 16 + quad * 4 + r) sacc[ct][r] = -1e30f;
            }
        }
        // online softmax (exp2), rows quad*4+r replicated across 16-lane group
        float mnew[4], alpha[4], psum[4];
#pragma unroll
        for (int r = 0; r < 4; ++r) {
            float vm = fmaxf(fmaxf(sacc[0][r], sacc[1][r]), fmaxf(sacc[2][r], sacc[3][r]));
            vm = fmaxf(vm, __shfl_xor(vm, 1));
            vm = fmaxf(vm, __shfl_xor(vm, 2));
            vm = fmaxf(vm, __shfl_xor(vm, 4));
            vm = fmaxf(vm, __shfl_xor(vm, 8));
            mnew[r] = fmaxf(m_i[r], vm);
            alpha[r] = __builtin_amdgcn_exp2f(m_i[r] - mnew[r]);
            m_i[r] = mnew[r];
            psum[r] = 0.f;
        }
#pragma unroll
        for (int ct = 0; ct < 4; ++ct)
#pragma unroll
            for (int r = 0; r < 4; ++r) {
                float p = __builtin_amdgcn_exp2f(sacc[ct][r] - mnew[r]);
                sacc[ct][r] = p;
                psum[r] += p;
            }
#pragma unroll
        for (int r = 0; r < 4; ++r) {
            float ps = psum[r];
            ps += __shfl_xor(ps, 1);
            ps += __shfl_xor(ps, 2);
            ps += __shfl_xor(ps, 4);
            ps += __shfl_xor(ps, 8);
            l_i[r] = alpha[r] * l_i[r] + ps;
        }
        // P -> LDS (stride 136B; wave-private rows, no barrier)
#pragma unroll
        for (int ct = 0; ct < 4; ++ct)
#pragma unroll
            for (int r = 0; r < 4; ++r)
                *(u16*)((char*)QPs + (w * 16 + quad * 4 + r) * 136 + (ct * 16 + lm) * 2)
                    = f2bf(sacc[ct][r]);
#pragma unroll
        for (int dt = 0; dt < 4; ++dt)
#pragma unroll
            for (int r = 0; r < 4; ++r) acc_o[dt][r] *= alpha[r];
        // O += P V : 8 MFMAs (Vts holds V^T tiles)
        short8 pf0 = *(const short8*)((const char*)QPs + (w * 16 + lm) * 136 +      quad * 16);
        short8 pf1 = *(const short8*)((const char*)QPs + (w * 16 + lm) * 136 + 64 + quad * 16);
#pragma unroll
        for (int dt = 0; dt < 4; ++dt) {
            short8 vf0 = *(const short8*)((const char*)Vts +        (dt * 16 + lm) * 64 + quad * 16);
            short8 vf1 = *(const short8*)((const char*)Vts + 4096 + (dt * 16 + lm) * 64 + quad * 16);
            acc_o[dt] = __builtin_amdgcn_mfma_f32_16x16x32_bf16(pf0, vf0, acc_o[dt], 0, 0, 0);
            acc_o[dt] = __builtin_amdgcn_mfma_f32_16x16x32_bf16(pf1, vf1, acc_o[dt], 0, 0, 0);
        }
    }
#pragma unroll
    for (int r = 0; r < 4; ++r) {
        const float inv = 1.f / l_i[r];
        const int row = q0 + w * 16 + quad * 4 + r;
#pragma unroll
        for (int dt = 0; dt < 4; ++dt)
            Ctx[(size_t)row * HID + h * HD + dt * 16 + lm] = f2bf(acc_o[dt][r] * inv);
    }
}

// ---------------------------------------------------------------------------
extern "C" void kernel_launch(void* const* d_in, const int* in_sizes, int n_in,
                              void* d_out, int out_size, void* d_ws, size_t ws_size,
                              hipStream_t stream) {
    const float* X   = (const float*)d_in[0];
    const int*   pos = (const int*)d_in[1];
    const float* Wq  = (const float*)d_in[2];
    const float* Wk  = (const float*)d_in[3];
    const float* Wv  = (const float*)d_in[4];
    const float* Wo  = (const float*)d_in[5];
    float* out = (float*)d_out;

    // ws (bf16 elems): Xb 4M | WqkvT 6M | WoT 4M | QK 5M | Vt 1M = 40 MB
    u16* Xb    = (u16*)d_ws;
    u16* WqkvT = Xb + (size_t)4194304;
    u16* WoT   = WqkvT + (size_t)6291456;
    u16* QK    = WoT + (size_t)4194304;
    u16* Vt    = QK + (size_t)S_LEN * QKD;
    u16* Ctxb  = Xb;   // Xb dead after QKV GEMM

    cast_bf16<<<2048, 256, 0, stream>>>(X, Xb, 524288);
    transpose_cast<<<dim3(64, 64), 256, 0, stream>>>(Wq, WqkvT, 2048, 2048);
    transpose_cast<<<dim3(16, 64), 256, 0, stream>>>(Wk, WqkvT + (size_t)2048 * 2048, 2048, 512);
    transpose_cast<<<dim3(16, 64), 256, 0, stream>>>(Wv, WqkvT + (size_t)2560 * 2048, 2048, 512);
    transpose_cast<<<dim3(64, 64), 256, 0, stream>>>(Wo, WoT, 2048, 2048);

    gemm_bt<1><<<dim3(24, 16), 256, 0, stream>>>(Xb, WqkvT, QK, Vt, 2048, 3072, 2048);

    rope_qk<<<10240, 256, 0, stream>>>(QK, pos);

    attn_mfma<<<dim3(32, 32), 256, 0, stream>>>(QK, Vt, Ctxb);

    gemm_bt<0><<<dim3(16, 16), 256, 0, stream>>>(Ctxb, WoT, out, nullptr, 2048, 2048, 2048);
}